// Round 11
// baseline (148.688 us; speedup 1.0000x reference)
//
#include <hip/hip_runtime.h>

// 3-level separable 2D DWT, bior3.5, mode='periodization'.
// out[i] = sum_j f[j] * x[(2i+1-j) mod N] along each axis.
// v11 = v10 + intra-wave LDS fences (race-hypothesis test).
//      One wave = 64-col output strip x OR rows; private LDS row buffers;
//      zero __syncthreads. 12-deep shift register, named-register staging.
//      Every LDS produce->consume edge is fenced with lgkmcnt(0) +
//      sched_barrier(0) (rule #18: clobber alone doesn't stop hipcc).

#define SQ2f 1.41421356237309504880f

// LDS ordering fence (wave-local): drain DS queue + full scheduling barrier.
#define LDSF() do {                                         \
    asm volatile("s_waitcnt lgkmcnt(0)" ::: "memory");      \
    __builtin_amdgcn_sched_barrier(0);                      \
  } while (0)

// Row pass for the two staged rows in buf0/buf1 -> shift-reg slots SA, SB.
// Window for lane's output col J: buf[2*lane+2 .. 2*lane+13] = x[2J-10..2J+1].
#define ROWPASS_TO(SA, SB) do {                                           \
    float w0[12], w1[12];                                                 \
    _Pragma("unroll")                                                     \
    for (int k_ = 0; k_ < 6; ++k_) {                                      \
      *(float2*)&w0[2*k_] = *(const float2*)&buf0[2*lane + 2 + 2*k_];     \
      *(float2*)&w1[2*k_] = *(const float2*)&buf1[2*lane + 2 + 2*k_];     \
    }                                                                     \
    float lo0 = 0.f, hi0 = 0.f, lo1 = 0.f, hi1 = 0.f;                     \
    _Pragma("unroll")                                                     \
    for (int jc_ = 0; jc_ < 12; ++jc_) {                                  \
      lo0 += c_lo[jc_] * w0[11 - jc_];                                    \
      lo1 += c_lo[jc_] * w1[11 - jc_];                                    \
    }                                                                     \
    _Pragma("unroll")                                                     \
    for (int k_ = 0; k_ < 4; ++k_) {                                      \
      hi0 += c_hi4[k_] * w0[7 - k_];                                      \
      hi1 += c_hi4[k_] * w1[7 - k_];                                      \
    }                                                                     \
    rl[SA] = lo0; rh[SA] = hi0; rl[SB] = lo1; rh[SB] = hi1;               \
  } while (0)

// Fenced store of a staged pair: WAR fence before, RAW fence after.
#define STPAIR_F(A, B) do { LDSF(); stpair(A, B); LDSF(); } while (0)

template <int N, int OR>
__global__ __launch_bounds__(256, 5) void dwt2_slide(
    const float* __restrict__ src,
    float* __restrict__ aa, float* __restrict__ da,
    float* __restrict__ ad, float* __restrict__ dd)
{
    constexpr float c_lo[12] = {
        -20.f * SQ2f / 2048.f,  60.f * SQ2f / 2048.f,   76.f * SQ2f / 2048.f,
        -388.f * SQ2f / 2048.f, -104.f * SQ2f / 2048.f, 1400.f * SQ2f / 2048.f,
        1400.f * SQ2f / 2048.f, -104.f * SQ2f / 2048.f, -388.f * SQ2f / 2048.f,
        76.f * SQ2f / 2048.f,   60.f * SQ2f / 2048.f,   -20.f * SQ2f / 2048.f };
    constexpr float c_hi4[4] = { -SQ2f / 8.f, 3.f * SQ2f / 8.f, -3.f * SQ2f / 8.f, SQ2f / 8.f };

    constexpr int h      = N >> 1;
    constexpr int mask   = N - 1;
    constexpr int STRIPS = h / 64;       // 64-col strips per image
    constexpr int BANDS  = h / OR;       // row bands per image

    const int wid  = blockIdx.x * 4 + (threadIdx.x >> 6);
    const int lane = threadIdx.x & 63;
    const int img  = wid / (STRIPS * BANDS);          // pow2 divide
    const int rem  = wid - img * (STRIPS * BANDS);
    const int strip = rem & (STRIPS - 1);
    const int band  = rem / STRIPS;

    __shared__ float s_buf[4][2][152];                // per-wave private
    float* buf0 = &s_buf[threadIdx.x >> 6][0][0];
    float* buf1 = &s_buf[threadIdx.x >> 6][1][0];

    const float* im = src + (unsigned)img * (unsigned)(N * N);
    const int cbase = strip * 128 - 12;               // first staged col (mult of 4)
    const int r0    = band * OR * 2 - 10;             // first staged row
    const bool ldr  = lane < 36;                      // 36 lanes x float4 = 144 cols
    const int qcol  = (cbase + 4 * lane) & mask;      // wrapped quad base (mult of 4)

    // pair pi = staged rows 2pi, 2pi+1 (globally wrapped)
    auto ldpair = [&](int pi, float4& a, float4& b) {
        if (ldr) {
            const int ra = (r0 + 2 * pi) & mask;
            const int rb = (r0 + 2 * pi + 1) & mask;
            a = *(const float4*)(im + (unsigned)(ra * N) + qcol);
            b = *(const float4*)(im + (unsigned)(rb * N) + qcol);
        }
    };
    auto stpair = [&](const float4& a, const float4& b) {
        if (ldr) {
            *(float4*)&buf0[4 * lane] = a;
            *(float4*)&buf1[4 * lane] = b;
        }
    };

    // shift register: rl[k]/rh[k] = row-pass(staged row 2*li + k), k = 0..11
    float rl[12], rh[12];
    float4 a0, b0, a1, b1, a2, b2;

    // ---- prologue: pairs 0..5 -> slots 0..11 (loads 3-deep in flight) ----
    ldpair(0, a0, b0); ldpair(1, a1, b1); ldpair(2, a2, b2);
    STPAIR_F(a0, b0); ROWPASS_TO(0, 1);   ldpair(3, a0, b0);
    STPAIR_F(a1, b1); ROWPASS_TO(2, 3);   ldpair(4, a1, b1);
    STPAIR_F(a2, b2); ROWPASS_TO(4, 5);   ldpair(5, a2, b2);
    STPAIR_F(a0, b0); ROWPASS_TO(6, 7);
    STPAIR_F(a1, b1); ROWPASS_TO(8, 9);
    STPAIR_F(a2, b2); ROWPASS_TO(10, 11);

    // ---- main loop: one output row per iteration ----
    for (int li = 0; li < OR; ++li) {
        // issue next pair's loads first; column pass below hides the latency
        if (li < OR - 1) ldpair(li + 6, a0, b0);
        __builtin_amdgcn_sched_barrier(0);   // pin the issue point

        // column pass: needs row-pass rows 2li..2li+11 == rl/rh[0..11]
        float vaa = 0.f, vad = 0.f;
        #pragma unroll
        for (int jr = 0; jr < 12; ++jr) {
            vaa += c_lo[jr] * rl[11 - jr];
            vad += c_lo[jr] * rh[11 - jr];
        }
        float vda = 0.f, vdd = 0.f;
        #pragma unroll
        for (int k = 0; k < 4; ++k) {
            vda += c_hi4[k] * rl[7 - k];
            vdd += c_hi4[k] * rh[7 - k];
        }
        const int orow = band * OR + li;
        const unsigned ob = (unsigned)((img * h + orow) * h + strip * 64 + lane);
        aa[ob] = vaa;
        da[ob] = vda;
        ad[ob] = vad;
        dd[ob] = vdd;

        if (li < OR - 1) {
            // shift down by 2, then row-pass the new pair into slots 10,11
            #pragma unroll
            for (int k = 0; k < 10; ++k) { rl[k] = rl[k + 2]; rh[k] = rh[k + 2]; }
            STPAIR_F(a0, b0);
            ROWPASS_TO(10, 11);
        }
    }
}

extern "C" void kernel_launch(void* const* d_in, const int* in_sizes, int n_in,
                              void* d_out, int out_size, void* d_ws, size_t ws_size,
                              hipStream_t stream) {
    const float* x = (const float*)d_in[0];
    float* out = (float*)d_out;
    float* ws  = (float*)d_ws;

    // 24 independent N x N images (8 batch x 3 channels).
    const size_t s512 = (size_t)24 * 512 * 512;
    const size_t s256 = (size_t)24 * 256 * 256;
    const size_t s128 = (size_t)24 * 128 * 128;

    // d_out layout (return order): a | h3(da,ad,dd) | h2(...) | h1(...)
    float* a_out = out;
    float* h3 = out + s128;
    float* h2 = out + 4 * s128;
    float* h1 = out + 4 * s128 + 3 * s256;

    float* aa1 = ws;          // 512^2 intermediate
    float* aa2 = ws + s512;   // 256^2 intermediate
    (void)in_sizes; (void)n_in; (void)out_size; (void)ws_size;

    dim3 blk(256, 1, 1);
    // level 1: 1024 -> 512. 8 strips * 32 bands * 24 = 6144 waves
    dwt2_slide<1024, 16><<<dim3(6144 / 4, 1, 1), blk, 0, stream>>>(
        x, aa1, h1, h1 + s512, h1 + 2 * s512);
    // level 2: 512 -> 256. 4 strips * 32 bands * 24 = 3072 waves
    dwt2_slide<512, 8><<<dim3(3072 / 4, 1, 1), blk, 0, stream>>>(
        aa1, aa2, h2, h2 + s256, h2 + 2 * s256);
    // level 3: 256 -> 128. 2 strips * 32 bands * 24 = 1536 waves
    dwt2_slide<256, 4><<<dim3(1536 / 4, 1, 1), blk, 0, stream>>>(
        aa2, a_out, h3, h3 + s128, h3 + 2 * s128);
}

// Round 12
// 88.850 us; speedup vs baseline: 1.6735x; 1.6735x over previous
//
#include <hip/hip_runtime.h>

// 3-level separable 2D DWT, bior3.5, mode='periodization'.
// out[i] = sum_j f[j] * x[(2i+1-j) mod N] along each axis.
// v12 = v11 with zero-cost fences + depth-2 load pipeline.
//   - Wave-autonomous: one wave = 64-col strip x OR rows, private LDS bufs,
//     zero __syncthreads, zero s_waitcnt in source.
//   - Fence = asm volatile("" ::: "memory") ONLY: HW executes a wave's DS ops
//     in order (same-address ds_write->ds_read RAW is safe); the compiler
//     fence just forbids hipcc reordering LDS reads across the exec-masked
//     LDS writes (v10's failure, fixed by v11's heavy fences, kept here free).
//   - Depth-2 prefetch: 2x-unrolled main loop, named A/B float4 pairs;
//     pair li+7 issued at iter li, consumed (stpair) at iter li+1.
//   - launch_bounds(256,4): VGPR cap 128 -> no spill (v5/v11 lesson).

#define SQ2f 1.41421356237309504880f

#define CFENCE() asm volatile("" ::: "memory")

// Row pass for the two staged rows in buf0/buf1 -> shift-reg slots SA, SB.
// Lane's output col J = strip*64+lane: window = buf[2*lane+2 .. 2*lane+13].
#define ROWPASS_TO(SA, SB) do {                                           \
    float w0[12], w1[12];                                                 \
    _Pragma("unroll")                                                     \
    for (int k_ = 0; k_ < 6; ++k_) {                                      \
      *(float2*)&w0[2*k_] = *(const float2*)&buf0[2*lane + 2 + 2*k_];     \
      *(float2*)&w1[2*k_] = *(const float2*)&buf1[2*lane + 2 + 2*k_];     \
    }                                                                     \
    float lo0 = 0.f, hi0 = 0.f, lo1 = 0.f, hi1 = 0.f;                     \
    _Pragma("unroll")                                                     \
    for (int jc_ = 0; jc_ < 12; ++jc_) {                                  \
      lo0 += c_lo[jc_] * w0[11 - jc_];                                    \
      lo1 += c_lo[jc_] * w1[11 - jc_];                                    \
    }                                                                     \
    _Pragma("unroll")                                                     \
    for (int k_ = 0; k_ < 4; ++k_) {                                      \
      hi0 += c_hi4[k_] * w0[7 - k_];                                      \
      hi1 += c_hi4[k_] * w1[7 - k_];                                      \
    }                                                                     \
    rl[SA] = lo0; rh[SA] = hi0; rl[SB] = lo1; rh[SB] = hi1;               \
  } while (0)

// Fenced staged-pair store: compiler-only barriers on both sides.
#define STPAIR_F(A, B) do { CFENCE(); stpair(A, B); CFENCE(); } while (0)

// Column pass + 4 subband stores for output row (band*OR + LI).
#define COLPASS(LI) do {                                                  \
    float vaa = 0.f, vad = 0.f;                                           \
    _Pragma("unroll")                                                     \
    for (int jr_ = 0; jr_ < 12; ++jr_) {                                  \
      vaa += c_lo[jr_] * rl[11 - jr_];                                    \
      vad += c_lo[jr_] * rh[11 - jr_];                                    \
    }                                                                     \
    float vda = 0.f, vdd = 0.f;                                           \
    _Pragma("unroll")                                                     \
    for (int k_ = 0; k_ < 4; ++k_) {                                      \
      vda += c_hi4[k_] * rl[7 - k_];                                      \
      vdd += c_hi4[k_] * rh[7 - k_];                                      \
    }                                                                     \
    const int orow_ = band * OR + (LI);                                   \
    const unsigned ob_ = (unsigned)((img * h + orow_) * h + strip * 64 + lane); \
    aa[ob_] = vaa;  da[ob_] = vda;  ad[ob_] = vad;  dd[ob_] = vdd;        \
  } while (0)

#define SHIFT2() do {                                                     \
    _Pragma("unroll")                                                     \
    for (int k_ = 0; k_ < 10; ++k_) { rl[k_] = rl[k_ + 2]; rh[k_] = rh[k_ + 2]; } \
  } while (0)

template <int N, int OR>
__global__ __launch_bounds__(256, 4) void dwt2_slide(
    const float* __restrict__ src,
    float* __restrict__ aa, float* __restrict__ da,
    float* __restrict__ ad, float* __restrict__ dd)
{
    constexpr float c_lo[12] = {
        -20.f * SQ2f / 2048.f,  60.f * SQ2f / 2048.f,   76.f * SQ2f / 2048.f,
        -388.f * SQ2f / 2048.f, -104.f * SQ2f / 2048.f, 1400.f * SQ2f / 2048.f,
        1400.f * SQ2f / 2048.f, -104.f * SQ2f / 2048.f, -388.f * SQ2f / 2048.f,
        76.f * SQ2f / 2048.f,   60.f * SQ2f / 2048.f,   -20.f * SQ2f / 2048.f };
    constexpr float c_hi4[4] = { -SQ2f / 8.f, 3.f * SQ2f / 8.f, -3.f * SQ2f / 8.f, SQ2f / 8.f };

    constexpr int h      = N >> 1;
    constexpr int mask   = N - 1;
    constexpr int STRIPS = h / 64;       // 64-col strips per image
    constexpr int BANDS  = h / OR;       // row bands per image

    const int wid  = blockIdx.x * 4 + (threadIdx.x >> 6);
    const int lane = threadIdx.x & 63;
    const int img  = wid / (STRIPS * BANDS);          // pow2 divide
    const int rem  = wid - img * (STRIPS * BANDS);
    const int strip = rem & (STRIPS - 1);
    const int band  = rem / STRIPS;

    __shared__ float s_buf[4][2][152];                // per-wave private
    float* buf0 = &s_buf[threadIdx.x >> 6][0][0];
    float* buf1 = &s_buf[threadIdx.x >> 6][1][0];

    const float* im = src + (unsigned)img * (unsigned)(N * N);
    const int cbase = strip * 128 - 12;               // first staged col (mult of 4)
    const int r0    = band * OR * 2 - 10;             // first staged row
    const bool ldr  = lane < 36;                      // 36 lanes x float4 = 144 cols
    const int qcol  = (cbase + 4 * lane) & mask;      // wrapped quad base (mult of 4)

    // pair pi = staged rows 2pi, 2pi+1 (globally wrapped)
    auto ldpair = [&](int pi, float4& a, float4& b) {
        if (ldr) {
            const int ra = (r0 + 2 * pi) & mask;
            const int rb = (r0 + 2 * pi + 1) & mask;
            a = *(const float4*)(im + (unsigned)(ra * N) + qcol);
            b = *(const float4*)(im + (unsigned)(rb * N) + qcol);
        }
    };
    auto stpair = [&](const float4& a, const float4& b) {
        if (ldr) {
            *(float4*)&buf0[4 * lane] = a;
            *(float4*)&buf1[4 * lane] = b;
        }
    };

    // shift register: rl[k]/rh[k] = row-pass(staged row 2*li + k), k = 0..11
    float rl[12], rh[12];
    float4 a0, b0, a1, b1, a2, b2;

    // ---- prologue: pairs 0..5 -> slots 0..11; A=(a0,b0) ends holding pair 6 ----
    ldpair(0, a0, b0); ldpair(1, a1, b1); ldpair(2, a2, b2);
    STPAIR_F(a0, b0); ROWPASS_TO(0, 1);   ldpair(3, a0, b0);
    STPAIR_F(a1, b1); ROWPASS_TO(2, 3);   ldpair(4, a1, b1);
    STPAIR_F(a2, b2); ROWPASS_TO(4, 5);   ldpair(5, a2, b2);
    STPAIR_F(a0, b0); ROWPASS_TO(6, 7);   ldpair(6, a0, b0);
    STPAIR_F(a1, b1); ROWPASS_TO(8, 9);
    STPAIR_F(a2, b2); ROWPASS_TO(10, 11);

    // ---- main: 2x unrolled; at iter li issue pair li+7, consume pair li+6 ----
    // even li: consume A=(a0,b0), load into B=(a1,b1); odd li: the reverse.
    for (int li = 0; li < OR; li += 2) {
        // even sub-iter
        if (li <= OR - 3) ldpair(li + 7, a1, b1);
        COLPASS(li);
        {   // li < OR-1 always (OR even)
            SHIFT2();
            STPAIR_F(a0, b0);                // pair li+6
            ROWPASS_TO(10, 11);
        }
        // odd sub-iter
        const int lj = li + 1;
        if (lj <= OR - 3) ldpair(lj + 7, a0, b0);
        COLPASS(lj);
        if (lj < OR - 1) {
            SHIFT2();
            STPAIR_F(a1, b1);                // pair lj+6
            ROWPASS_TO(10, 11);
        }
    }
}

extern "C" void kernel_launch(void* const* d_in, const int* in_sizes, int n_in,
                              void* d_out, int out_size, void* d_ws, size_t ws_size,
                              hipStream_t stream) {
    const float* x = (const float*)d_in[0];
    float* out = (float*)d_out;
    float* ws  = (float*)d_ws;

    // 24 independent N x N images (8 batch x 3 channels).
    const size_t s512 = (size_t)24 * 512 * 512;
    const size_t s256 = (size_t)24 * 256 * 256;
    const size_t s128 = (size_t)24 * 128 * 128;

    // d_out layout (return order): a | h3(da,ad,dd) | h2(...) | h1(...)
    float* a_out = out;
    float* h3 = out + s128;
    float* h2 = out + 4 * s128;
    float* h1 = out + 4 * s128 + 3 * s256;

    float* aa1 = ws;          // 512^2 intermediate
    float* aa2 = ws + s512;   // 256^2 intermediate
    (void)in_sizes; (void)n_in; (void)out_size; (void)ws_size;

    dim3 blk(256, 1, 1);
    // level 1: 1024 -> 512. 8 strips * 16 bands * 24 = 3072 waves (768 blocks)
    dwt2_slide<1024, 32><<<dim3(3072 / 4, 1, 1), blk, 0, stream>>>(
        x, aa1, h1, h1 + s512, h1 + 2 * s512);
    // level 2: 512 -> 256. 4 strips * 16 bands * 24 = 1536 waves (384 blocks)
    dwt2_slide<512, 16><<<dim3(1536 / 4, 1, 1), blk, 0, stream>>>(
        aa1, aa2, h2, h2 + s256, h2 + 2 * s256);
    // level 3: 256 -> 128. 2 strips * 16 bands * 24 = 768 waves (192 blocks)
    dwt2_slide<256, 8><<<dim3(768 / 4, 1, 1), blk, 0, stream>>>(
        aa2, a_out, h3, h3 + s128, h3 + 2 * s128);
}